// Round 5
// baseline (508.768 us; speedup 1.0000x reference)
//
#include <hip/hip_runtime.h>
#include <math.h>

#define B_   8
#define C_   768
#define T_   1024
#define NH_  12
#define DH_  64
#define BT_  (B_*T_)       // 8192
#define WSZ  (C_*C_)       // 589824 per weight matrix

using bf16x8 = __attribute__((ext_vector_type(8))) short;
using f32x4  = __attribute__((ext_vector_type(4))) float;
using f32x16 = __attribute__((ext_vector_type(16))) float;
typedef unsigned short u16;

// ---- bf16 split helpers (round-to-nearest-even) ----
__device__ inline u16 bf16_hi(float x) {
    unsigned u = __builtin_bit_cast(unsigned, x);
    u = (u + 0x7fffu + ((u >> 16) & 1u)) >> 16;
    return (u16)u;
}
__device__ inline float bf16_f(u16 h) {
    unsigned u = ((unsigned)h) << 16;
    return __builtin_bit_cast(float, u);
}
__device__ inline void split_bf16(float x, u16& h, u16& l) {
    h = bf16_hi(x);
    l = bf16_hi(x - bf16_f(h));
}

// async global->LDS, 16 B per lane; LDS dst = wave-uniform base + lane*16
__device__ __forceinline__ void async_load16(const void* gp, void* lp) {
    __builtin_amdgcn_global_load_lds(
        (const __attribute__((address_space(1))) unsigned int*)gp,
        (__attribute__((address_space(3))) unsigned int*)lp, 16, 0, 0);
}

// ---------------------------------------------------------------------------
// Kernel 0: all 5 weight mats fp32 -> bf16 hi/lo split in one launch.
// ---------------------------------------------------------------------------
__global__ __launch_bounds__(256) void wconv_all(
    const float* __restrict__ W0, const float* __restrict__ W1,
    const float* __restrict__ W2, const float* __restrict__ W3,
    const float* __restrict__ W4, u16* __restrict__ wbuf) {
    int mat = blockIdx.y;
    const float* W = (mat == 0) ? W0 : (mat == 1) ? W1 : (mat == 2) ? W2
                   : (mat == 3) ? W3 : W4;
    u16* hi = wbuf + (size_t)mat * 2 * WSZ;
    u16* lo = hi + WSZ;
    int i = (blockIdx.x * 256 + threadIdx.x) * 4;
    float4 w = *(const float4*)(W + i);
    ushort4 h, l;
    split_bf16(w.x, h.x, l.x);
    split_bf16(w.y, h.y, l.y);
    split_bf16(w.z, h.z, l.z);
    split_bf16(w.w, h.w, l.w);
    *(ushort4*)(hi + i) = h;
    *(ushort4*)(lo + i) = l;
}

// ---------------------------------------------------------------------------
// Kernel 1: LayerNorm with (B,C,T)->(B*T,C) transpose; writes bf16 hi/lo.
// ---------------------------------------------------------------------------
__global__ __launch_bounds__(256) void ln_kernel(const float* __restrict__ x,
                                                 const float* __restrict__ gamma,
                                                 const float* __restrict__ beta,
                                                 u16* __restrict__ xh,
                                                 u16* __restrict__ xl) {
    int row = blockIdx.x;
    int b = row >> 10;
    int t = row & 1023;
    int tid = threadIdx.x;
    const float* xb = x + (size_t)b * C_ * T_ + t;
    float v0 = xb[(size_t)(tid      ) * T_];
    float v1 = xb[(size_t)(tid + 256) * T_];
    float v2 = xb[(size_t)(tid + 512) * T_];
    float s  = v0 + v1 + v2;
    float sq = v0 * v0 + v1 * v1 + v2 * v2;
    #pragma unroll
    for (int m = 1; m < 64; m <<= 1) {
        s  += __shfl_xor(s,  m);
        sq += __shfl_xor(sq, m);
    }
    __shared__ float ss[4], ssq[4];
    int wid = tid >> 6;
    if ((tid & 63) == 0) { ss[wid] = s; ssq[wid] = sq; }
    __syncthreads();
    s  = ss[0] + ss[1] + ss[2] + ss[3];
    sq = ssq[0] + ssq[1] + ssq[2] + ssq[3];
    float mu   = s * (1.0f / 768.0f);
    float var  = sq * (1.0f / 768.0f) - mu * mu;
    float rstd = 1.0f / sqrtf(var + 1e-5f);
    size_t o = (size_t)row * C_;
    float r0 = (v0 - mu) * rstd * gamma[tid      ] + beta[tid      ];
    float r1 = (v1 - mu) * rstd * gamma[tid + 256] + beta[tid + 256];
    float r2 = (v2 - mu) * rstd * gamma[tid + 512] + beta[tid + 512];
    u16 h, l;
    split_bf16(r0, h, l); xh[o + tid      ] = h; xl[o + tid      ] = l;
    split_bf16(r1, h, l); xh[o + tid + 256] = h; xl[o + tid + 256] = l;
    split_bf16(r2, h, l); xh[o + tid + 512] = h; xl[o + tid + 512] = l;
}

// ---------------------------------------------------------------------------
// Kernel 2: fused QKVG GEMM, split-bf16, 32x32x16 MFMA.
// Fragment-ordered LDS (1 KB = one 32x16 fragment, lane-major) staged by
// global_load_lds width 16; wave-specialized staging (wave i -> array i).
// 2x2 waves, each 64x64 via 2x2 of 32x32; BK=32 (2 k16 slices).
// mat 0/1: q/k bf16 hi/lo token-major (q pre-scaled 1/8);
// mat 2:   operands swapped -> V^T [b,h,d,t] bf16 hi/lo;
// mat 3:   bf16 pre-sigmoid gate.
// ---------------------------------------------------------------------------
__global__ __launch_bounds__(256, 2) void qkvg_mfma(
    const u16* __restrict__ xh, const u16* __restrict__ xl,
    const u16* __restrict__ wmats,
    const float* __restrict__ bq, const float* __restrict__ bk,
    const float* __restrict__ bv, const float* __restrict__ bg,
    u16* __restrict__ qh, u16* __restrict__ ql,
    u16* __restrict__ kh, u16* __restrict__ kl,
    u16* __restrict__ vth, u16* __restrict__ vtl,
    u16* __restrict__ g) {
    int bx = blockIdx.x;            // m tile 0..63
    int by = blockIdx.y;            // 0..23
    int mat = by / 6;
    int n0  = (by % 6) * 128;
    int m0  = bx * 128;
    const u16* Wh = wmats + (size_t)mat * 2 * WSZ;
    const u16* Wl = Wh + WSZ;
    const float* bias = (mat == 0) ? bq : (mat == 1) ? bk : (mat == 2) ? bv : bg;

    __shared__ u16 Ah[4096], Al[4096], Bh[4096], Bl[4096];

    int tid  = threadIdx.x;
    int lane = tid & 63, wid = tid >> 6;
    int wm = (wid & 1) * 64, wn = (wid >> 1) * 64;

    f32x16 acc[2][2];
    #pragma unroll
    for (int i = 0; i < 2; ++i)
        #pragma unroll
        for (int j = 0; j < 2; ++j)
            acc[i][j] = (f32x16){0.f,0.f,0.f,0.f,0.f,0.f,0.f,0.f,
                                 0.f,0.f,0.f,0.f,0.f,0.f,0.f,0.f};

    // staging setup: wave 0->Ah(xh), 1->Al(xl), 2->Bh(Wh), 3->Bl(Wl)
    const u16* gsrc = (wid == 0) ? xh : (wid == 1) ? xl : (wid == 2) ? Wh : Wl;
    u16* lbase = (wid == 0) ? Ah : (wid == 1) ? Al : (wid == 2) ? Bh : Bl;
    int rbase = (wid < 2) ? m0 : n0;
    // per-lane: row += lane&31, k += (lane>>5)*8
    size_t lanesrc = (size_t)(rbase + (lane & 31)) * 768 + (lane >> 5) * 8;

    int ga = wm >> 5, gb = wn >> 5;   // fragment row/col group bases

    for (int k0 = 0; k0 < 768; k0 += 32) {
        #pragma unroll
        for (int j = 0; j < 8; ++j) {
            int s = j >> 2, grp = j & 3;
            const u16* gp = gsrc + lanesrc + (size_t)grp * 32 * 768 + k0 + s * 16;
            async_load16(gp, (char*)lbase + j * 1024);
        }
        __syncthreads();
        #pragma unroll
        for (int s = 0; s < 2; ++s) {
            bf16x8 fah[2], fal[2], fbh[2], fbl[2];
            #pragma unroll
            for (int i = 0; i < 2; ++i) {
                fah[i] = *(const bf16x8*)((const char*)Ah + (s*4 + ga + i) * 1024 + lane * 16);
                fal[i] = *(const bf16x8*)((const char*)Al + (s*4 + ga + i) * 1024 + lane * 16);
                fbh[i] = *(const bf16x8*)((const char*)Bh + (s*4 + gb + i) * 1024 + lane * 16);
                fbl[i] = *(const bf16x8*)((const char*)Bl + (s*4 + gb + i) * 1024 + lane * 16);
            }
            if (mat == 2) {
                #pragma unroll
                for (int mi = 0; mi < 2; ++mi)
                    #pragma unroll
                    for (int ni = 0; ni < 2; ++ni) {
                        acc[mi][ni] = __builtin_amdgcn_mfma_f32_32x32x16_bf16(fbh[ni], fah[mi], acc[mi][ni], 0, 0, 0);
                        acc[mi][ni] = __builtin_amdgcn_mfma_f32_32x32x16_bf16(fbh[ni], fal[mi], acc[mi][ni], 0, 0, 0);
                        acc[mi][ni] = __builtin_amdgcn_mfma_f32_32x32x16_bf16(fbl[ni], fah[mi], acc[mi][ni], 0, 0, 0);
                    }
            } else {
                #pragma unroll
                for (int mi = 0; mi < 2; ++mi)
                    #pragma unroll
                    for (int ni = 0; ni < 2; ++ni) {
                        acc[mi][ni] = __builtin_amdgcn_mfma_f32_32x32x16_bf16(fah[mi], fbh[ni], acc[mi][ni], 0, 0, 0);
                        acc[mi][ni] = __builtin_amdgcn_mfma_f32_32x32x16_bf16(fah[mi], fbl[ni], acc[mi][ni], 0, 0, 0);
                        acc[mi][ni] = __builtin_amdgcn_mfma_f32_32x32x16_bf16(fal[mi], fbh[ni], acc[mi][ni], 0, 0, 0);
                    }
            }
        }
        __syncthreads();
    }
    // epilogue: 32x32 C/D: col = lane&31, row = (reg&3) + 8*(reg>>2) + 4*(lane>>5)
    int col = lane & 31, rof = (lane >> 5) * 4;
    if (mat == 2) {
        int bb = m0 >> 10;
        #pragma unroll
        for (int mi = 0; mi < 2; ++mi) {
            int tok = m0 + wm + mi * 32 + col;
            int tl  = tok & 1023;
            #pragma unroll
            for (int ni = 0; ni < 2; ++ni) {
                #pragma unroll
                for (int rg = 0; rg < 16; ++rg) {
                    int ch = n0 + wn + ni * 32 + (rg & 3) + 8 * (rg >> 2) + rof;
                    float val = acc[mi][ni][rg] + bias[ch];
                    size_t addr = ((size_t)((bb * 12 + (ch >> 6)) * 64 + (ch & 63))) * 1024 + tl;
                    u16 h, l;
                    split_bf16(val, h, l);
                    vth[addr] = h;
                    vtl[addr] = l;
                }
            }
        }
    } else {
        u16* oh = (mat == 0) ? qh : (mat == 1) ? kh : g;
        u16* ol = (mat == 0) ? ql : kl;
        #pragma unroll
        for (int ni = 0; ni < 2; ++ni) {
            int ch = n0 + wn + ni * 32 + col;
            float bb = bias[ch];
            #pragma unroll
            for (int mi = 0; mi < 2; ++mi) {
                #pragma unroll
                for (int rg = 0; rg < 16; ++rg) {
                    int tok = m0 + wm + mi * 32 + (rg & 3) + 8 * (rg >> 2) + rof;
                    float val = acc[mi][ni][rg] + bb;
                    size_t addr = (size_t)tok * 768 + ch;
                    if (mat == 3) {
                        g[addr] = bf16_hi(val);
                    } else {
                        if (mat == 0) val *= 0.125f;
                        u16 h, l;
                        split_bf16(val, h, l);
                        oh[addr] = h;
                        ol[addr] = l;
                    }
                }
            }
        }
    }
}

// ---------------------------------------------------------------------------
// Kernel 3: MFMA flash attention (16x16x32) + bf16 sigmoid gate.
// Q fragments loaded straight to registers (wave-row-matched).
// K/V in separate fragment-ordered LDS buffers staged by global_load_lds
// (wave i stages array i) -> 2 barriers per KV stage.
// P strip is wave-private LDS (no barrier for its round-trip).
// ---------------------------------------------------------------------------
__global__ __launch_bounds__(256, 3) void attn_mfma(
    const u16* __restrict__ qhg, const u16* __restrict__ qlg,
    const u16* __restrict__ khg, const u16* __restrict__ klg,
    const u16* __restrict__ vthg, const u16* __restrict__ vtlg,
    const u16* __restrict__ gbf,
    u16* __restrict__ yh, u16* __restrict__ yl) {
    int qt = blockIdx.x;   // 0..15
    int h  = blockIdx.y;   // 0..11
    int b  = blockIdx.z;   // 0..7
    __shared__ u16 Kh[4096], Kl[4096], Vh[4096], Vl[4096];
    __shared__ u16 Ps[64 * 72];
    int tid = threadIdx.x;
    int lane = tid & 63, w = tid >> 6;
    int fr = lane & 15, quad = lane >> 4, fq = quad * 8;

    size_t qbase = ((size_t)(b * 1024 + qt * 64)) * 768 + h * 64;
    size_t kbase = ((size_t)(b * 1024)) * 768 + h * 64;
    size_t vbase = ((size_t)((b * 12 + h) * 64)) * 1024;

    // Q A-fragments direct from global (loop-invariant)
    bf16x8 aqh[2], aql[2];
    #pragma unroll
    for (int kk = 0; kk < 2; ++kk) {
        size_t off = qbase + (size_t)(w * 16 + fr) * 768 + kk * 32 + fq;
        aqh[kk] = *(const bf16x8*)(qhg + off);
        aql[kk] = *(const bf16x8*)(qlg + off);
    }
    float m_i[4], l_i[4];
    f32x4 Oacc[4];
    #pragma unroll
    for (int i = 0; i < 4; ++i) {
        m_i[i] = -1e30f; l_i[i] = 0.0f;
        Oacc[i] = (f32x4){0.f, 0.f, 0.f, 0.f};
    }

    // staging setup: wave 0->Kh, 1->Kl, 2->Vh, 3->Vl
    const u16* gsrc = (w == 0) ? khg : (w == 1) ? klg : (w == 2) ? vthg : vtlg;
    u16* lbase = (w == 0) ? Kh : (w == 1) ? Kl : (w == 2) ? Vh : Vl;
    bool isV = (w >= 2);
    // K op j (s2=j>>2, nt=j&3): addr = kbase + (st*64+nt*16+fr)*768 + s2*32 + fq
    // V op j (s2=j>>2, dn=j&3): addr = vbase + (dn*16+fr)*1024 + st*64 + s2*32 + fq
    size_t lanebase  = isV ? (vbase + (size_t)fr * 1024 + fq)
                           : (kbase + (size_t)fr * 768 + fq);
    size_t st_stride  = isV ? 64 : (size_t)64 * 768;
    size_t grp_stride = isV ? 16384 : (size_t)16 * 768;

    for (int st = 0; st < 16; ++st) {
        __syncthreads();   // previous stage's K/V reads complete
        #pragma unroll
        for (int j = 0; j < 8; ++j) {
            int s2 = j >> 2, grp = j & 3;
            const u16* gp = gsrc + lanebase + (size_t)st * st_stride
                          + (size_t)grp * grp_stride + s2 * 32;
            async_load16(gp, (char*)lbase + j * 1024);
        }
        __syncthreads();   // staged (vmcnt drained) and visible
        // S = Q K^T (wave strip 16 x 64), 3-MFMA split
        f32x4 sacc[4];
        #pragma unroll
        for (int nt = 0; nt < 4; ++nt) sacc[nt] = (f32x4){0.f, 0.f, 0.f, 0.f};
        #pragma unroll
        for (int nt = 0; nt < 4; ++nt)
            #pragma unroll
            for (int kk = 0; kk < 2; ++kk) {
                bf16x8 kbh = *(const bf16x8*)((const char*)Kh + (kk*4 + nt) * 1024 + lane * 16);
                bf16x8 kbl = *(const bf16x8*)((const char*)Kl + (kk*4 + nt) * 1024 + lane * 16);
                sacc[nt] = __builtin_amdgcn_mfma_f32_16x16x32_bf16(aqh[kk], kbh, sacc[nt], 0, 0, 0);
                sacc[nt] = __builtin_amdgcn_mfma_f32_16x16x32_bf16(aqh[kk], kbl, sacc[nt], 0, 0, 0);
                sacc[nt] = __builtin_amdgcn_mfma_f32_16x16x32_bf16(aql[kk], kbh, sacc[nt], 0, 0, 0);
            }
        // online softmax per owned row (row = w*16 + quad*4 + rg)
        #pragma unroll
        for (int rg = 0; rg < 4; ++rg) {
            float mx = fmaxf(fmaxf(sacc[0][rg], sacc[1][rg]),
                             fmaxf(sacc[2][rg], sacc[3][rg]));
            #pragma unroll
            for (int msk = 1; msk < 16; msk <<= 1) mx = fmaxf(mx, __shfl_xor(mx, msk));
            float mn = fmaxf(m_i[rg], mx);
            float al = __expf(m_i[rg] - mn);
            float p0 = __expf(sacc[0][rg] - mn);
            float p1 = __expf(sacc[1][rg] - mn);
            float p2 = __expf(sacc[2][rg] - mn);
            float p3 = __expf(sacc[3][rg] - mn);
            float rs = p0 + p1 + p2 + p3;
            #pragma unroll
            for (int msk = 1; msk < 16; msk <<= 1) rs += __shfl_xor(rs, msk);
            l_i[rg] = l_i[rg] * al + rs;
            m_i[rg] = mn;
            #pragma unroll
            for (int dn = 0; dn < 4; ++dn) Oacc[dn][rg] *= al;
            int row = w * 16 + quad * 4 + rg;
            Ps[row * 72 +  0 + fr] = bf16_hi(p0);
            Ps[row * 72 + 16 + fr] = bf16_hi(p1);
            Ps[row * 72 + 32 + fr] = bf16_hi(p2);
            Ps[row * 72 + 48 + fr] = bf16_hi(p3);
        }
        // O += P V (P wave-private; V staged this stage)
        #pragma unroll
        for (int kk = 0; kk < 2; ++kk) {
            bf16x8 pa = *(const bf16x8*)&Ps[(w * 16 + fr) * 72 + fq + kk * 32];
            #pragma unroll
            for (int dn = 0; dn < 4; ++dn) {
                bf16x8 vbh = *(const bf16x8*)((const char*)Vh + (kk*4 + dn) * 1024 + lane * 16);
                bf16x8 vbl = *(const bf16x8*)((const char*)Vl + (kk*4 + dn) * 1024 + lane * 16);
                Oacc[dn] = __builtin_amdgcn_mfma_f32_16x16x32_bf16(pa, vbh, Oacc[dn], 0, 0, 0);
                Oacc[dn] = __builtin_amdgcn_mfma_f32_16x16x32_bf16(pa, vbl, Oacc[dn], 0, 0, 0);
            }
        }
    }
    // epilogue: normalize, sigmoid gate, split-store y
    float inv[4];
    #pragma unroll
    for (int rg = 0; rg < 4; ++rg) inv[rg] = 1.0f / l_i[rg];
    #pragma unroll
    for (int dn = 0; dn < 4; ++dn) {
        int ch = h * 64 + dn * 16 + fr;
        #pragma unroll
        for (int rg = 0; rg < 4; ++rg) {
            int tok = b * 1024 + qt * 64 + w * 16 + quad * 4 + rg;
            float gv = bf16_f(gbf[(size_t)tok * 768 + ch]);
            float sg = 1.0f / (1.0f + __expf(-gv));
            float val = Oacc[dn][rg] * inv[rg] * sg;
            u16 hh, ll;
            split_bf16(val, hh, ll);
            yh[(size_t)tok * 768 + ch] = hh;
            yl[(size_t)tok * 768 + ch] = ll;
        }
    }
}

// ---------------------------------------------------------------------------
// Kernel 4: out = y @ Wo^T + bo -> (B, C, T), split-bf16 32x32x16 MFMA,
// same fragment-ordered global_load_lds structure as qkvg.
// A = Wo (c rows), B = y (token rows) -> stores coalesced along t.
// ---------------------------------------------------------------------------
__global__ __launch_bounds__(256, 2) void out_mfma(
    const u16* __restrict__ yh, const u16* __restrict__ yl,
    const u16* __restrict__ woh, const u16* __restrict__ wol,
    const float* __restrict__ bo, float* __restrict__ out) {
    int bx = blockIdx.x;   // c tile 0..5
    int by = blockIdx.y;   // t tile 0..63
    int m0 = bx * 128;     // c
    int n0 = by * 128;     // t

    __shared__ u16 Ah[4096], Al[4096], Bh[4096], Bl[4096];

    int tid  = threadIdx.x;
    int lane = tid & 63, wid = tid >> 6;
    int wm = (wid & 1) * 64, wn = (wid >> 1) * 64;

    f32x16 acc[2][2];
    #pragma unroll
    for (int i = 0; i < 2; ++i)
        #pragma unroll
        for (int j = 0; j < 2; ++j)
            acc[i][j] = (f32x16){0.f,0.f,0.f,0.f,0.f,0.f,0.f,0.f,
                                 0.f,0.f,0.f,0.f,0.f,0.f,0.f,0.f};

    const u16* gsrc = (wid == 0) ? woh : (wid == 1) ? wol : (wid == 2) ? yh : yl;
    u16* lbase = (wid == 0) ? Ah : (wid == 1) ? Al : (wid == 2) ? Bh : Bl;
    int rbase = (wid < 2) ? m0 : n0;
    size_t lanesrc = (size_t)(rbase + (lane & 31)) * 768 + (lane >> 5) * 8;
    int ga = wm >> 5, gb = wn >> 5;

    for (int k0 = 0; k0 < 768; k0 += 32) {
        #pragma unroll
        for (int j = 0; j < 8; ++j) {
            int s = j >> 2, grp = j & 3;
            const u16* gp = gsrc + lanesrc + (size_t)grp * 32 * 768 + k0 + s * 16;
            async_load16(gp, (char*)lbase + j * 1024);
        }
        __syncthreads();
        #pragma unroll
        for (int s = 0; s < 2; ++s) {
            bf16x8 fah[2], fal[2], fbh[2], fbl[2];
            #pragma unroll
            for (int i = 0; i < 2; ++i) {
                fah[i] = *(const bf16x8*)((const char*)Ah + (s*4 + ga + i) * 1024 + lane * 16);
                fal[i] = *(const bf16x8*)((const char*)Al + (s*4 + ga + i) * 1024 + lane * 16);
                fbh[i] = *(const bf16x8*)((const char*)Bh + (s*4 + gb + i) * 1024 + lane * 16);
                fbl[i] = *(const bf16x8*)((const char*)Bl + (s*4 + gb + i) * 1024 + lane * 16);
            }
            #pragma unroll
            for (int mi = 0; mi < 2; ++mi)
                #pragma unroll
                for (int ni = 0; ni < 2; ++ni) {
                    acc[mi][ni] = __builtin_amdgcn_mfma_f32_32x32x16_bf16(fah[mi], fbh[ni], acc[mi][ni], 0, 0, 0);
                    acc[mi][ni] = __builtin_amdgcn_mfma_f32_32x32x16_bf16(fah[mi], fbl[ni], acc[mi][ni], 0, 0, 0);
                    acc[mi][ni] = __builtin_amdgcn_mfma_f32_32x32x16_bf16(fal[mi], fbh[ni], acc[mi][ni], 0, 0, 0);
                }
        }
        __syncthreads();
    }
    int col = lane & 31, rof = (lane >> 5) * 4;
    int bb = n0 >> 10;
    #pragma unroll
    for (int ni = 0; ni < 2; ++ni) {
        int tok = n0 + wn + ni * 32 + col;
        int tl = tok & 1023;
        #pragma unroll
        for (int mi = 0; mi < 2; ++mi) {
            #pragma unroll
            for (int rg = 0; rg < 16; ++rg) {
                int c = m0 + wm + mi * 32 + (rg & 3) + 8 * (rg >> 2) + rof;
                float val = acc[mi][ni][rg] + bo[c];
                out[((size_t)bb * 768 + c) * 1024 + tl] = val;
            }
        }
    }
}

extern "C" void kernel_launch(void* const* d_in, const int* in_sizes, int n_in,
                              void* d_out, int out_size, void* d_ws, size_t ws_size,
                              hipStream_t stream) {
    const float* x     = (const float*)d_in[0];
    const float* Wq    = (const float*)d_in[1];
    const float* bq    = (const float*)d_in[2];
    const float* Wk    = (const float*)d_in[3];
    const float* bk    = (const float*)d_in[4];
    const float* Wv    = (const float*)d_in[5];
    const float* bv    = (const float*)d_in[6];
    const float* Wo    = (const float*)d_in[7];
    const float* bo    = (const float*)d_in[8];
    const float* Wg    = (const float*)d_in[9];
    const float* bg    = (const float*)d_in[10];
    const float* gamma = (const float*)d_in[11];
    const float* beta  = (const float*)d_in[12];
    float* out = (float*)d_out;

    // workspace (ushort): xn_h|xn_l|qh|ql|kh|kl|vth|vtl|g | wbuf
    const size_t S = (size_t)BT_ * C_;
    u16* xn_hi = (u16*)d_ws;
    u16* xn_lo = xn_hi + S;
    u16* qh    = xn_lo + S;
    u16* ql    = qh + S;
    u16* kh    = ql + S;
    u16* kl    = kh + S;
    u16* vth   = kl + S;
    u16* vtl   = vth + S;
    u16* g_bf  = vtl + S;
    u16* wbuf  = g_bf + S;   // [Wq,Wk,Wv,Wg,Wo] x {hi,lo}
    u16* y_hi  = xn_hi;      // alias: xn dead after qkvg
    u16* y_lo  = xn_lo;

    wconv_all<<<dim3(WSZ / 1024, 5), 256, 0, stream>>>(Wq, Wk, Wv, Wg, Wo, wbuf);
    ln_kernel<<<BT_, 256, 0, stream>>>(x, gamma, beta, xn_hi, xn_lo);
    qkvg_mfma<<<dim3(64, 24), 256, 0, stream>>>(xn_hi, xn_lo, wbuf,
                                                bq, bk, bv, bg,
                                                qh, ql, kh, kl, vth, vtl, g_bf);
    attn_mfma<<<dim3(16, 12, 8), 256, 0, stream>>>(qh, ql, kh, kl, vth, vtl,
                                                   g_bf, y_hi, y_lo);
    out_mfma<<<dim3(6, 64), 256, 0, stream>>>(y_hi, y_lo,
                                              wbuf + (size_t)8 * WSZ,
                                              wbuf + (size_t)9 * WSZ, bo, out);
}